// Round 10
// baseline (695.098 us; speedup 1.0000x reference)
//
#include <hip/hip_runtime.h>
#include <math.h>

#define BB 32
#define TT 128
#define NTOK 30
#define DD 512
#define C2F 2.885390081777927f   // 2*log2(e): tanh(x) = 1 - 2/(1+2^(C2F*x))

#define REP 8   // measurement loops; production build sets 1 and keeps only the winner

typedef unsigned short u16;
typedef __attribute__((ext_vector_type(8))) short bf16x8;
typedef __attribute__((ext_vector_type(8))) unsigned short u16x8;
typedef __attribute__((ext_vector_type(4))) float f32x4;
typedef __attribute__((ext_vector_type(2))) _Float16 h16x2;

__device__ __forceinline__ u16 f2bf(float f) {
    unsigned u = __builtin_bit_cast(unsigned, f);
    u += 0x7fffu + ((u >> 16) & 1u);          // RNE
    return (u16)(u >> 16);
}
__device__ __forceinline__ float bf2f(u16 u) {
    return __builtin_bit_cast(float, (unsigned)u << 16);
}
__device__ __forceinline__ u16 f2h(float f) {
    return __builtin_bit_cast(u16, (_Float16)f);
}
__device__ __forceinline__ float h2f(u16 u) {
    return (float)__builtin_bit_cast(_Float16, u);
}

__device__ __forceinline__ void load_lds16(const u16* g, u16* l) {
    __builtin_amdgcn_global_load_lds(
        (const __attribute__((address_space(1))) unsigned int*)g,
        (__attribute__((address_space(3))) unsigned int*)l,
        16, 0, 0);
}

template<int CTRL>
__device__ __forceinline__ float dpp_add(float x) {
    int yi = __builtin_amdgcn_update_dpp(0, __builtin_bit_cast(int, x), CTRL, 0xF, 0xF, true);
    return x + __builtin_bit_cast(float, yi);
}
// full 64-lane reduce, result in all lanes (DPP + 2 shfl)
__device__ __forceinline__ float red64(float x) {
    x = dpp_add<0xB1>(x);
    x = dpp_add<0x4E>(x);
    x = dpp_add<0x141>(x);
    x = dpp_add<0x140>(x);
    x += __shfl_xor(x, 16, 64);
    x += __shfl_xor(x, 32, 64);
    return x;
}
// 64-lane reduce via DPP row_bcast; true total only in lane 63 -> readlane broadcast
__device__ __forceinline__ float red64_bcast(float x) {
    x = dpp_add<0xB1>(x);
    x = dpp_add<0x4E>(x);
    x = dpp_add<0x141>(x);
    x = dpp_add<0x140>(x);
    x = dpp_add<0x142>(x);   // row_bcast15
    x = dpp_add<0x143>(x);   // row_bcast31
    int xi = __builtin_amdgcn_readlane(__builtin_bit_cast(int, x), 63);
    return __builtin_bit_cast(float, xi);
}

#define KEEP(x) asm volatile("" :: "v"(x))

// ---------------- prep: activation bf16 casts + weight transposes ----------------
#define NCONV ((BB*NTOK*DD + BB*TT*DD)/4/256)
__global__ __launch_bounds__(256) void prep(
    const float* __restrict__ h_s, const float* __restrict__ h_v,
    const float* __restrict__ W_S, const float* __restrict__ W_V,
    u16* __restrict__ Abf_s, u16* __restrict__ Abf_v,
    u16* __restrict__ WtS, u16* __restrict__ WtV)
{
    __shared__ u16 tile[32][33];
    int bx = blockIdx.x;
    if (bx < NCONV) {
        int i = bx * 256 + threadIdx.x;
        const int n0_4 = BB * NTOK * DD / 4;
        const float* x; u16* y;
        if (i < n0_4) { x = h_s; y = Abf_s; }
        else { i -= n0_4; x = h_v; y = Abf_v; }
        float4 v = ((const float4*)x)[i];
        ushort4 o;
        o.x = f2bf(v.x); o.y = f2bf(v.y); o.z = f2bf(v.z); o.w = f2bf(v.w);
        ((ushort4*)y)[i] = o;
        return;
    }
    int idx = bx - NCONV;
    const float* W = (idx & 256) ? W_V : W_S;
    u16*        T  = (idx & 256) ? WtV : WtS;
    idx &= 255;
    int k0 = (idx >> 4) * 32, n0 = (idx & 15) * 32;
    int c = threadIdx.x & 31, r8 = threadIdx.x >> 5;
    #pragma unroll
    for (int q = 0; q < 4; ++q) {
        int k = r8 + q * 8;
        tile[k][c] = f2bf(W[(size_t)(k0 + k) * DD + n0 + c]);
    }
    __syncthreads();
    #pragma unroll
    for (int q = 0; q < 4; ++q) {
        int n = r8 + q * 8;
        T[(size_t)(n0 + n) * DD + k0 + c] = tile[c][n];
    }
}

// ---------------- bf16 MFMA GEMM -> f16 output (pre-scaled by C2F) ----------------
__global__ __launch_bounds__(256) void gemm_mfma(
    const u16* __restrict__ Abf_s, const u16* __restrict__ Abf_v,
    const u16* __restrict__ WtS, const u16* __restrict__ WtV,
    const float* __restrict__ b_S, const float* __restrict__ b_V,
    u16* __restrict__ Sh, u16* __restrict__ Vh)
{
    __shared__ u16 ldsA[64 * 64];
    __shared__ u16 ldsB[64 * 64];
    const int bid = blockIdx.x;
    const int grp = bid >> 6, rem = bid & 63;
    const int by  = rem >> 3;
    const int bxx = grp * 8 + (rem & 7);
    if (bxx >= 15 + 64) return;
    const u16* A; const u16* Bt; const float* bias; u16* Y; int bm;
    if (bxx < 15) { A = Abf_s; Bt = WtS; bias = b_S; Y = Sh; bm = bxx * 64; }
    else          { A = Abf_v; Bt = WtV; bias = b_V; Y = Vh; bm = (bxx - 15) * 64; }
    const int bn = by * 64;

    const int tid  = threadIdx.x;
    const int lane = tid & 63;
    const int wid  = tid >> 6;
    const int wr = wid >> 1, wc = wid & 1;

    const int idx0 = tid,       row0 = idx0 >> 3, ch0 = (idx0 & 7) ^ (row0 & 7);
    const int idx1 = 256 + tid, row1 = idx1 >> 3, ch1 = (idx1 & 7) ^ (row1 & 7);
    const u16* gA0 = A  + (size_t)(bm + row0) * DD + ch0 * 8;
    const u16* gA1 = A  + (size_t)(bm + row1) * DD + ch1 * 8;
    const u16* gB0 = Bt + (size_t)(bn + row0) * DD + ch0 * 8;
    const u16* gB1 = Bt + (size_t)(bn + row1) * DD + ch1 * 8;
    u16* lA0 = ldsA + wid * 512;
    u16* lA1 = ldsA + 2048 + wid * 512;
    u16* lB0 = ldsB + wid * 512;
    u16* lB1 = ldsB + 2048 + wid * 512;

    const int arow = wr * 32 + (lane & 15);
    const int brow = wc * 32 + (lane & 15);
    const int kq   = lane >> 4;
    const int sw   = lane & 7;

    f32x4 acc[2][2];
    #pragma unroll
    for (int i = 0; i < 2; ++i)
        #pragma unroll
        for (int j = 0; j < 2; ++j)
            acc[i][j] = (f32x4){0.f, 0.f, 0.f, 0.f};

    for (int k0 = 0; k0 < DD; k0 += 64) {
        __syncthreads();
        load_lds16(gA0 + k0, lA0);
        load_lds16(gA1 + k0, lA1);
        load_lds16(gB0 + k0, lB0);
        load_lds16(gB1 + k0, lB1);
        __syncthreads();

        bf16x8 af[2][2], bfr[2][2];
        #pragma unroll
        for (int i = 0; i < 2; ++i)
            #pragma unroll
            for (int s = 0; s < 2; ++s) {
                int ra = arow + i * 16;
                af[i][s]  = *(const bf16x8*)(ldsA + ra * 64 + ((s * 4 + kq) ^ sw) * 8);
                int rb = brow + i * 16;
                bfr[i][s] = *(const bf16x8*)(ldsB + rb * 64 + ((s * 4 + kq) ^ sw) * 8);
            }
        #pragma unroll
        for (int s = 0; s < 2; ++s)
            #pragma unroll
            for (int i = 0; i < 2; ++i)
                #pragma unroll
                for (int j = 0; j < 2; ++j)
                    acc[i][j] = __builtin_amdgcn_mfma_f32_16x16x32_bf16(
                        af[i][s], bfr[j][s], acc[i][j], 0, 0, 0);
    }

    #pragma unroll
    for (int i = 0; i < 2; ++i)
        #pragma unroll
        for (int j = 0; j < 2; ++j) {
            int r = bm + wr * 32 + i * 16 + (lane >> 4) * 4;
            int c = bn + wc * 32 + j * 16 + (lane & 15);
            float bv = bias[c];
            #pragma unroll
            for (int reg = 0; reg < 4; ++reg)
                Y[(size_t)(r + reg) * DD + c] = f2h((acc[i][j][reg] + bv) * C2F);
        }
}

// =======================================================================
// attend variants. Common structure: block=(b, 8 t), wave per t, 8 d/lane.
// VARIANT 0: f16 packed (attend5)   -> real output
// VARIANT 1: scalar f32 math        -> keep-alive only
// VARIANT 2: beta phase only        -> keep-alive only
// VARIANT 3: no beta (stage+softmax+PV) -> keep-alive only
// VARIANT 4: scalar + bcast-reduce  -> keep-alive only
// =======================================================================
template<int VARIANT>
__global__ __launch_bounds__(512) void attend_v(
    const u16* __restrict__ Sh, const u16* __restrict__ Vh,
    const u16* __restrict__ Hbf, const int* __restrict__ lengths,
    const float* __restrict__ W_w, const float* __restrict__ b_w,
    float* __restrict__ out)
{
    __shared__ u16 Sl[NTOK * DD];
    __shared__ u16 Hl[NTOK * DD];
    const int b  = blockIdx.x >> 4;
    const int tc = blockIdx.x & 15;
    const int tid  = threadIdx.x;
    const int w    = tid >> 6;
    const int lane = tid & 63;
    const int t_glob = tc * 8 + w;
    const int len = lengths[b];
    const int d0 = lane * 8;
    const float bwv = b_w[0];

    for (int rep = 0; rep < REP; ++rep) {
        // ---- stage S (f16) and H (bf16, unless VARIANT==2) ----
        {
            const uint4* sS = (const uint4*)(Sh + (size_t)b * NTOK * DD);
            const uint4* sH = (const uint4*)(Hbf + (size_t)b * NTOK * DD);
            uint4* dS = (uint4*)Sl;
            uint4* dH = (uint4*)Hl;
            #pragma unroll
            for (int i = 0; i < 4; ++i) {
                int idx = i * 512 + tid;
                if (idx < NTOK * DD / 8) {
                    dS[idx] = sS[idx];
                    if (VARIANT != 2) dH[idx] = sH[idx];
                }
            }
        }

        // ---- V row and W_w ----
        float v[8], ww[8], wsum;
        h16x2 vv[4], w2[4];
        {
            u16x8 v8 = *(const u16x8*)(Vh + ((size_t)(b * TT + t_glob)) * DD + d0);
            float4 w0 = *(const float4*)&W_w[d0];
            float4 w1 = *(const float4*)&W_w[d0 + 4];
            float wwf[8] = {w0.x, w0.y, w0.z, w0.w, w1.x, w1.y, w1.z, w1.w};
            #pragma unroll
            for (int j = 0; j < 8; ++j) { v[j] = h2f(v8[j]); ww[j] = wwf[j]; }
            #pragma unroll
            for (int p = 0; p < 4; ++p) {
                vv[p] = __builtin_bit_cast(h16x2, ((const unsigned int*)&v8)[p]);
                w2[p] = (h16x2){(_Float16)wwf[2 * p], (_Float16)wwf[2 * p + 1]};
            }
            float wpart = 0.f;
            #pragma unroll
            for (int j = 0; j < 8; ++j) wpart += wwf[j];
            wsum = (VARIANT == 4) ? red64_bcast(wpart) : red64(wpart);
        }

        __syncthreads();

        // ---- beta partials ----
        float pacc[NTOK];
        if (VARIANT == 3) {
            #pragma unroll
            for (int n = 0; n < NTOK; ++n) {
                u16x8 s8 = *(const u16x8*)(Sl + n * DD + d0);
                pacc[n] = h2f(s8[0]);          // fake beta, no exp/reduce
            }
        } else if (VARIANT == 0) {
            const h16x2 one2 = (h16x2){(_Float16)1.0f, (_Float16)1.0f};
            #pragma unroll
            for (int n = 0; n < NTOK; ++n) {
                u16x8 s8 = *(const u16x8*)(Sl + n * DD + d0);
                float a = 0.f;
                #pragma unroll
                for (int p = 0; p < 4; ++p) {
                    h16x2 s2 = __builtin_bit_cast(h16x2, ((const unsigned int*)&s8)[p]);
                    h16x2 t = s2 + vv[p];
                    h16x2 e;
                    e.x = __builtin_elementwise_exp2(t.x);
                    e.y = __builtin_elementwise_exp2(t.y);
                    h16x2 f = e + one2;
                    h16x2 r;
                    r.x = __builtin_amdgcn_rcph(f.x);
                    r.y = __builtin_amdgcn_rcph(f.y);
                    a = __builtin_amdgcn_fdot2(r, w2[p], a, false);
                }
                pacc[n] = red64(a);
            }
        } else {  // V1, V2, V4: scalar f32 math
            #pragma unroll
            for (int n = 0; n < NTOK; ++n) {
                u16x8 s8 = *(const u16x8*)(Sl + n * DD + d0);
                float a = 0.f;
                #pragma unroll
                for (int j = 0; j < 8; ++j) {
                    float e = __builtin_amdgcn_exp2f(h2f(s8[j]) + v[j]);
                    a = fmaf(ww[j], __builtin_amdgcn_rcpf(1.f + e), a);
                }
                pacc[n] = (VARIANT == 4) ? red64_bcast(a) : red64(a);
            }
        }

        if (VARIANT == 2) {
            #pragma unroll
            for (int n = 0; n < NTOK; ++n) KEEP(pacc[n]);
            __syncthreads();
            continue;
        }

        // ---- softmax ----
        float mx = -1e30f;
        #pragma unroll
        for (int n = 0; n < NTOK; ++n) {
            float bn = fmaf(-2.f, pacc[n], wsum + bwv);
            pacc[n] = bn;
            if (n < len) mx = fmaxf(mx, bn);
        }
        float ssum = 0.f;
        #pragma unroll
        for (int n = 0; n < NTOK; ++n) {
            float e = (n < len) ? __expf(pacc[n] - mx) : 0.f;
            pacc[n] = e;
            ssum += e;
        }
        const float inv = 1.f / (ssum + 1e-13f);
        #pragma unroll
        for (int n = 0; n < NTOK; ++n) pacc[n] = fmaf(pacc[n], inv, 1e-13f);

        // ---- PV ----
        float acc8[8] = {};
        #pragma unroll
        for (int n = 0; n < NTOK; ++n) {
            float a = pacc[n];
            u16x8 h8 = *(const u16x8*)(Hl + n * DD + d0);
            #pragma unroll
            for (int j = 0; j < 8; ++j)
                acc8[j] = fmaf(a, bf2f(h8[j]), acc8[j]);
        }
        if (VARIANT == 0) {
            float* Or = out + ((size_t)(b * TT + t_glob)) * DD + d0;
            *(float4*)&Or[0] = make_float4(acc8[0], acc8[1], acc8[2], acc8[3]);
            *(float4*)&Or[4] = make_float4(acc8[4], acc8[5], acc8[6], acc8[7]);
        } else {
            #pragma unroll
            for (int j = 0; j < 8; ++j) KEEP(acc8[j]);
        }
        __syncthreads();
    }
}

extern "C" void kernel_launch(void* const* d_in, const int* in_sizes, int n_in,
                              void* d_out, int out_size, void* d_ws, size_t ws_size,
                              hipStream_t stream) {
    const float* h_s     = (const float*)d_in[0];
    const float* h_v     = (const float*)d_in[1];
    const int*   lengths = (const int*)  d_in[2];
    const float* W_S     = (const float*)d_in[3];
    const float* b_S     = (const float*)d_in[4];
    const float* W_V     = (const float*)d_in[5];
    const float* b_V     = (const float*)d_in[6];
    const float* W_w     = (const float*)d_in[7];
    const float* b_w     = (const float*)d_in[8];
    float* out = (float*)d_out;

    u16* Sh    = (u16*)d_ws;
    u16* Vh    = Sh + (size_t)BB * NTOK * DD;
    u16* WtS   = Vh + (size_t)BB * TT * DD;
    u16* WtV   = WtS + (size_t)DD * DD;
    u16* Abf_s = WtV + (size_t)DD * DD;
    u16* Abf_v = Abf_s + (size_t)BB * NTOK * DD;

    prep<<<NCONV + 512, 256, 0, stream>>>(h_s, h_v, W_S, W_V, Abf_s, Abf_v, WtS, WtV);
    gemm_mfma<<<640, 256, 0, stream>>>(
        Abf_s, Abf_v, WtS, WtV, b_S, b_V, Sh, Vh);

    attend_v<0><<<BB * 16, 512, 0, stream>>>(Sh, Vh, Abf_s, lengths, W_w, b_w, out);
    attend_v<1><<<BB * 16, 512, 0, stream>>>(Sh, Vh, Abf_s, lengths, W_w, b_w, out);
    attend_v<2><<<BB * 16, 512, 0, stream>>>(Sh, Vh, Abf_s, lengths, W_w, b_w, out);
    attend_v<3><<<BB * 16, 512, 0, stream>>>(Sh, Vh, Abf_s, lengths, W_w, b_w, out);
    attend_v<4><<<BB * 16, 512, 0, stream>>>(Sh, Vh, Abf_s, lengths, W_w, b_w, out);
}

// Round 11
// 41.503 us; speedup vs baseline: 16.7483x; 16.7483x over previous
//
#include <hip/hip_runtime.h>
#include <math.h>

#define BB 32
#define TT 128
#define NTOK 30
#define DD 512
#define C2F 2.885390081777927f   // 2*log2(e): tanh(x) = 1 - 2/(1+2^(C2F*x))

typedef unsigned short u16;
typedef __attribute__((ext_vector_type(8))) short bf16x8;
typedef __attribute__((ext_vector_type(8))) unsigned short u16x8;
typedef __attribute__((ext_vector_type(4))) float f32x4;

__device__ __forceinline__ u16 f2bf(float f) {
    unsigned u = __builtin_bit_cast(unsigned, f);
    u += 0x7fffu + ((u >> 16) & 1u);          // RNE
    return (u16)(u >> 16);
}
__device__ __forceinline__ float bf2f(u16 u) {
    return __builtin_bit_cast(float, (unsigned)u << 16);
}
__device__ __forceinline__ u16 f2h(float f) {
    return __builtin_bit_cast(u16, (_Float16)f);
}
__device__ __forceinline__ float h2f(u16 u) {
    return (float)__builtin_bit_cast(_Float16, u);
}

__device__ __forceinline__ void load_lds16(const u16* g, u16* l) {
    __builtin_amdgcn_global_load_lds(
        (const __attribute__((address_space(1))) unsigned int*)g,
        (__attribute__((address_space(3))) unsigned int*)l,
        16, 0, 0);
}

template<int CTRL>
__device__ __forceinline__ float dpp_add(float x) {
    int yi = __builtin_amdgcn_update_dpp(0, __builtin_bit_cast(int, x), CTRL, 0xF, 0xF, true);
    return x + __builtin_bit_cast(float, yi);
}
__device__ __forceinline__ float red64(float x) {
    x = dpp_add<0xB1>(x);    // quad_perm xor1
    x = dpp_add<0x4E>(x);    // quad_perm xor2
    x = dpp_add<0x141>(x);   // row_half_mirror
    x = dpp_add<0x140>(x);   // row_mirror
    x += __shfl_xor(x, 16, 64);
    x += __shfl_xor(x, 32, 64);
    return x;
}

// ---------------- prep: activation bf16 casts + weight transposes ----------------
#define NCONV ((BB*NTOK*DD + BB*TT*DD)/4/256)   // 2528 blocks
__global__ __launch_bounds__(256) void prep(
    const float* __restrict__ h_s, const float* __restrict__ h_v,
    const float* __restrict__ W_S, const float* __restrict__ W_V,
    u16* __restrict__ Abf_s, u16* __restrict__ Abf_v,
    u16* __restrict__ WtS, u16* __restrict__ WtV)
{
    __shared__ u16 tile[32][33];
    int bx = blockIdx.x;
    if (bx < NCONV) {
        int i = bx * 256 + threadIdx.x;
        const int n0_4 = BB * NTOK * DD / 4;
        const float* x; u16* y;
        if (i < n0_4) { x = h_s; y = Abf_s; }
        else { i -= n0_4; x = h_v; y = Abf_v; }
        float4 v = ((const float4*)x)[i];
        ushort4 o;
        o.x = f2bf(v.x); o.y = f2bf(v.y); o.z = f2bf(v.z); o.w = f2bf(v.w);
        ((ushort4*)y)[i] = o;
        return;
    }
    int idx = bx - NCONV;
    const float* W = (idx & 256) ? W_V : W_S;
    u16*        T  = (idx & 256) ? WtV : WtS;
    idx &= 255;
    int k0 = (idx >> 4) * 32, n0 = (idx & 15) * 32;
    int c = threadIdx.x & 31, r8 = threadIdx.x >> 5;
    #pragma unroll
    for (int q = 0; q < 4; ++q) {
        int k = r8 + q * 8;
        tile[k][c] = f2bf(W[(size_t)(k0 + k) * DD + n0 + c]);
    }
    __syncthreads();
    #pragma unroll
    for (int q = 0; q < 4; ++q) {
        int n = r8 + q * 8;
        T[(size_t)(n0 + n) * DD + k0 + c] = tile[c][n];
    }
}

// ---------------- bf16 MFMA GEMM -> f16 output (pre-scaled by C2F) ----------------
__global__ __launch_bounds__(256) void gemm_mfma(
    const u16* __restrict__ Abf_s, const u16* __restrict__ Abf_v,
    const u16* __restrict__ WtS, const u16* __restrict__ WtV,
    const float* __restrict__ b_S, const float* __restrict__ b_V,
    u16* __restrict__ Sh, u16* __restrict__ Vh)
{
    __shared__ u16 ldsA[64 * 64];
    __shared__ u16 ldsB[64 * 64];
    const int bid = blockIdx.x;
    const int grp = bid >> 6, rem = bid & 63;
    const int by  = rem >> 3;
    const int bxx = grp * 8 + (rem & 7);       // panel-sharing blocks: same bid%8 -> same XCD
    if (bxx >= 15 + 64) return;
    const u16* A; const u16* Bt; const float* bias; u16* Y; int bm;
    if (bxx < 15) { A = Abf_s; Bt = WtS; bias = b_S; Y = Sh; bm = bxx * 64; }
    else          { A = Abf_v; Bt = WtV; bias = b_V; Y = Vh; bm = (bxx - 15) * 64; }
    const int bn = by * 64;

    const int tid  = threadIdx.x;
    const int lane = tid & 63;
    const int wid  = tid >> 6;
    const int wr = wid >> 1, wc = wid & 1;

    const int idx0 = tid,       row0 = idx0 >> 3, ch0 = (idx0 & 7) ^ (row0 & 7);
    const int idx1 = 256 + tid, row1 = idx1 >> 3, ch1 = (idx1 & 7) ^ (row1 & 7);
    const u16* gA0 = A  + (size_t)(bm + row0) * DD + ch0 * 8;
    const u16* gA1 = A  + (size_t)(bm + row1) * DD + ch1 * 8;
    const u16* gB0 = Bt + (size_t)(bn + row0) * DD + ch0 * 8;
    const u16* gB1 = Bt + (size_t)(bn + row1) * DD + ch1 * 8;
    u16* lA0 = ldsA + wid * 512;
    u16* lA1 = ldsA + 2048 + wid * 512;
    u16* lB0 = ldsB + wid * 512;
    u16* lB1 = ldsB + 2048 + wid * 512;

    const int arow = wr * 32 + (lane & 15);
    const int brow = wc * 32 + (lane & 15);
    const int kq   = lane >> 4;
    const int sw   = lane & 7;

    f32x4 acc[2][2];
    #pragma unroll
    for (int i = 0; i < 2; ++i)
        #pragma unroll
        for (int j = 0; j < 2; ++j)
            acc[i][j] = (f32x4){0.f, 0.f, 0.f, 0.f};

    for (int k0 = 0; k0 < DD; k0 += 64) {
        __syncthreads();
        load_lds16(gA0 + k0, lA0);
        load_lds16(gA1 + k0, lA1);
        load_lds16(gB0 + k0, lB0);
        load_lds16(gB1 + k0, lB1);
        __syncthreads();

        bf16x8 af[2][2], bfr[2][2];
        #pragma unroll
        for (int i = 0; i < 2; ++i)
            #pragma unroll
            for (int s = 0; s < 2; ++s) {
                int ra = arow + i * 16;
                af[i][s]  = *(const bf16x8*)(ldsA + ra * 64 + ((s * 4 + kq) ^ sw) * 8);
                int rb = brow + i * 16;
                bfr[i][s] = *(const bf16x8*)(ldsB + rb * 64 + ((s * 4 + kq) ^ sw) * 8);
            }
        #pragma unroll
        for (int s = 0; s < 2; ++s)
            #pragma unroll
            for (int i = 0; i < 2; ++i)
                #pragma unroll
                for (int j = 0; j < 2; ++j)
                    acc[i][j] = __builtin_amdgcn_mfma_f32_16x16x32_bf16(
                        af[i][s], bfr[j][s], acc[i][j], 0, 0, 0);
    }

    #pragma unroll
    for (int i = 0; i < 2; ++i)
        #pragma unroll
        for (int j = 0; j < 2; ++j) {
            int r = bm + wr * 32 + i * 16 + (lane >> 4) * 4;
            int c = bn + wc * 32 + j * 16 + (lane & 15);
            float bv = bias[c];
            #pragma unroll
            for (int reg = 0; reg < 4; ++reg)
                Y[(size_t)(r + reg) * DD + c] = f2h((acc[i][j][reg] + bv) * C2F);
        }
}

// ---------------- attend6: no LDS, wave per (b,t), reads via L2 ----------------
// 1024 blocks x 256 thr (4 waves). b = bid&31 -> all 128 blocks of a batch share
// bid%8 -> same XCD L2 (S[b]+H[b] = 60KB, L2-resident).
__global__ __launch_bounds__(256) void attend6(
    const u16* __restrict__ Sh, const u16* __restrict__ Vh,
    const u16* __restrict__ Hbf, const int* __restrict__ lengths,
    const float* __restrict__ W_w, const float* __restrict__ b_w,
    float* __restrict__ out)
{
    const int bid  = blockIdx.x;
    const int b    = bid & 31;
    const int tq   = bid >> 5;                 // 0..31
    const int wv   = threadIdx.x >> 6;         // 0..3
    const int lane = threadIdx.x & 63;
    const int t    = tq * 4 + wv;
    const int len  = lengths[b];
    const int d0   = lane * 8;
    const float bwv = b_w[0];

    const u16* Srow = Sh  + (size_t)b * NTOK * DD + d0;
    const u16* Hrow = Hbf + (size_t)b * NTOK * DD + d0;

    // V row (f16, pre-scaled) and W_w (f32)
    float v[8], ww[8];
    {
        u16x8 v8 = *(const u16x8*)(Vh + ((size_t)(b * TT + t)) * DD + d0);
        float4 w0 = *(const float4*)&W_w[d0];
        float4 w1 = *(const float4*)&W_w[d0 + 4];
        #pragma unroll
        for (int j = 0; j < 8; ++j) v[j] = h2f(v8[j]);
        ww[0]=w0.x; ww[1]=w0.y; ww[2]=w0.z; ww[3]=w0.w;
        ww[4]=w1.x; ww[5]=w1.y; ww[6]=w1.z; ww[7]=w1.w;
    }
    float wpart = 0.f;
    #pragma unroll
    for (int j = 0; j < 8; ++j) wpart += ww[j];
    const float wsum = red64(wpart);

    // beta partials: a = sum_d w_d * rcp(1 + 2^(S'+V'))
    float pacc[NTOK];
    #pragma unroll
    for (int n = 0; n < NTOK; ++n) {
        u16x8 s8 = *(const u16x8*)(Srow + (size_t)n * DD);
        float a = 0.f;
        #pragma unroll
        for (int j = 0; j < 8; ++j) {
            float e = __builtin_amdgcn_exp2f(h2f(s8[j]) + v[j]);
            a = fmaf(ww[j], __builtin_amdgcn_rcpf(1.f + e), a);
        }
        pacc[n] = red64(a);
    }

    // beta[n] = wsum + b_w - 2*pacc[n]; masked softmax; alpha
    float mx = -1e30f;
    #pragma unroll
    for (int n = 0; n < NTOK; ++n) {
        float bn = fmaf(-2.f, pacc[n], wsum + bwv);
        pacc[n] = bn;
        if (n < len) mx = fmaxf(mx, bn);
    }
    float ssum = 0.f;
    #pragma unroll
    for (int n = 0; n < NTOK; ++n) {
        float e = (n < len) ? __expf(pacc[n] - mx) : 0.f;
        pacc[n] = e;
        ssum += e;
    }
    const float inv = 1.f / (ssum + 1e-13f);
    #pragma unroll
    for (int n = 0; n < NTOK; ++n) pacc[n] = fmaf(pacc[n], inv, 1e-13f);

    // out[t] = sum_n alpha[n] * h_s[n]  (bf16 H via L2)
    float acc8[8] = {};
    #pragma unroll
    for (int n = 0; n < NTOK; ++n) {
        float a = pacc[n];
        u16x8 h8 = *(const u16x8*)(Hrow + (size_t)n * DD);
        #pragma unroll
        for (int j = 0; j < 8; ++j)
            acc8[j] = fmaf(a, bf2f(h8[j]), acc8[j]);
    }
    float* Or = out + ((size_t)(b * TT + t)) * DD + d0;
    *(float4*)&Or[0] = make_float4(acc8[0], acc8[1], acc8[2], acc8[3]);
    *(float4*)&Or[4] = make_float4(acc8[4], acc8[5], acc8[6], acc8[7]);
}

extern "C" void kernel_launch(void* const* d_in, const int* in_sizes, int n_in,
                              void* d_out, int out_size, void* d_ws, size_t ws_size,
                              hipStream_t stream) {
    const float* h_s     = (const float*)d_in[0];
    const float* h_v     = (const float*)d_in[1];
    const int*   lengths = (const int*)  d_in[2];
    const float* W_S     = (const float*)d_in[3];
    const float* b_S     = (const float*)d_in[4];
    const float* W_V     = (const float*)d_in[5];
    const float* b_V     = (const float*)d_in[6];
    const float* W_w     = (const float*)d_in[7];
    const float* b_w     = (const float*)d_in[8];
    float* out = (float*)d_out;

    // workspace: Sh | Vh (f16, prescaled) | WtS | WtV | Abf_s | Abf_v (bf16)
    u16* Sh    = (u16*)d_ws;
    u16* Vh    = Sh + (size_t)BB * NTOK * DD;
    u16* WtS   = Vh + (size_t)BB * TT * DD;
    u16* WtV   = WtS + (size_t)DD * DD;
    u16* Abf_s = WtV + (size_t)DD * DD;
    u16* Abf_v = Abf_s + (size_t)BB * NTOK * DD;

    prep<<<NCONV + 512, 256, 0, stream>>>(h_s, h_v, W_S, W_V, Abf_s, Abf_v, WtS, WtV);
    gemm_mfma<<<640, 256, 0, stream>>>(
        Abf_s, Abf_v, WtS, WtV, b_S, b_V, Sh, Vh);
    attend6<<<1024, 256, 0, stream>>>(Sh, Vh, Abf_s, lengths, W_w, b_w, out);
}